// Round 15
// baseline (134.462 us; speedup 1.0000x reference)
//
#include <hip/hip_runtime.h>

// LNSNet forward, R14: kill conv2's 1.5-round residency tail.
//  k2: 512-thr blocks can only fit 4/CU (32-wave cap) -> 1024 co-resident,
//      but grid was 1536 -> half-idle second round. Now 768 blocks x 2 chunks
//      (R8's rep-loop shape). Single round.
//  k1: prep/transpose blocks moved to grid front (finish early, no straggle).
//  Everything else identical to R13.
// Standing: no device-scope fences (R6/R9); no launch_bounds forcing (R10).

#define B 512
#define POS 676
#define ICP 36
#define P2SZ (64*12*12)
#define SCR 26
#define IMS 58
#define IMCOPY (54 * IMS)

typedef unsigned short ushort_t;
typedef ushort_t ushort4v __attribute__((ext_vector_type(4)));
typedef short s16x8 __attribute__((ext_vector_type(8)));
typedef float f32x4 __attribute__((ext_vector_type(4)));

__device__ __forceinline__ ushort_t f2bf(float f) {
    union { float f; unsigned u; } a; a.f = f;
    unsigned r = a.u + 0x7FFFu + ((a.u >> 16) & 1u);
    return (ushort_t)(r >> 16);
}
__device__ __forceinline__ float bf2f(ushort_t u) {
    union { unsigned u; float f; } a; a.u = ((unsigned)u) << 16;
    return a.f;
}

#define N_WR (64 * 9 * 32)
#define WR_BLOCKS 72
#define TR_BLOCKS 128
#define PRE_BLOCKS (WR_BLOCKS + TR_BLOCKS)   // 200, placed first
#define CONV1_BLOCKS 1024

// ---------------- k1: [wr prep | fc1-W transpose | conv1 MFMA] ----------------
__global__ __launch_bounds__(256) void conv1_prep(const float* __restrict__ x,
                                                  const float* __restrict__ w,
                                                  const float* __restrict__ bias,
                                                  const float* __restrict__ c2w,
                                                  const float* __restrict__ f1w,
                                                  ushort_t* __restrict__ out,
                                                  ushort_t* __restrict__ wr,
                                                  ushort_t* __restrict__ wfb) {
    __shared__ char smem[64 * 145 * 4];
    int blk = blockIdx.x;
    int tid = threadIdx.x;

    if (blk < WR_BLOCKS) {
        int t = blk * 256 + tid;
        int ic  = t & 31;
        int tap = (t >> 5) % 9;
        int oc  = t / 288;
        wr[t] = f2bf(c2w[oc * 288 + ic * 9 + tap]);
        return;
    }
    if (blk < PRE_BLOCKS) {
        // fc1 W transpose via LDS tile: row n, (oc,pos) -> k' = pos*64+oc
        float* tr = reinterpret_cast<float*>(smem);
        int n = blk - WR_BLOCKS;
        const float* src = f1w + (size_t)n * 9216;
#pragma unroll
        for (int i = 0; i < 36; ++i) {
            int idx = i * 256 + tid;
            int oc = idx / 144, pos = idx - oc * 144;
            tr[oc * 145 + pos] = src[idx];
        }
        __syncthreads();
        ushort_t* dst = wfb + (size_t)n * 9216;
#pragma unroll
        for (int i = 0; i < 36; ++i) {
            int idx = i * 256 + tid;
            int pos = idx >> 6, oc = idx & 63;
            dst[idx] = f2bf(tr[oc * 145 + pos]);
        }
        return;
    }

    // ================= conv1 via MFMA (R13 form) =================
    ushort_t* lds = reinterpret_cast<ushort_t*>(smem);
    int cb   = blk - PRE_BLOCKS;
    int b    = cb >> 1;
    int half = cb & 1;

    const float* xim = x + (size_t)b * 2916;
    for (int i = tid; i < 2916; i += 256) {
        int r = i / 54, c = i - r * 54;
        ushort_t v = f2bf(xim[i]);
        lds[r * IMS + c] = v;
        if (c > 0) lds[IMCOPY + r * IMS + c - 1] = v;
    }

    int lane = tid & 63, wid = tid >> 6;
    int quad = lane >> 4, lr = lane & 15;

    s16x8 bfrag[2];
#pragma unroll
    for (int n = 0; n < 2; ++n) {
        union { ushort_t u[8]; s16x8 v; } bu;
#pragma unroll
        for (int j = 0; j < 8; ++j) bu.u[j] = 0;
        if (quad < 3) {
            const float* wp = w + (n * 16 + lr) * 9 + quad * 3;
            bu.u[0] = f2bf(wp[0]);
            bu.u[1] = f2bf(wp[1]);
            bu.u[2] = f2bf(wp[2]);
        }
        bfrag[n] = bu.v;
    }
    float bv0 = bias[lr], bv1 = bias[16 + lr];

    __syncthreads();

    int cbase = (lr & 1) ? (IMCOPY + lr - 1) : lr;

    for (int py_l = wid; py_l < 13; py_l += 4) {
        int py = half * 13 + py_l;
        int y0 = 2 * py;
#pragma unroll
        for (int t = 0; t < 4; ++t) {
            int x0 = t * 16;
            int off0 = cbase + x0 + (y0 + quad) * IMS;
            int off1 = off0 + IMS;
            union { unsigned d[4]; s16x8 v; } a0, a1;
            a0.d[0] = *reinterpret_cast<const unsigned*>(&lds[off0]);
            a0.d[1] = *reinterpret_cast<const unsigned*>(&lds[off0 + 2]);
            a0.d[2] = a0.d[0]; a0.d[3] = a0.d[1];
            a1.d[0] = *reinterpret_cast<const unsigned*>(&lds[off1]);
            a1.d[1] = *reinterpret_cast<const unsigned*>(&lds[off1 + 2]);
            a1.d[2] = a1.d[0]; a1.d[3] = a1.d[1];

            f32x4 cA0 = (f32x4){0.f,0.f,0.f,0.f}, cA1 = cA0, cB0 = cA0, cB1 = cA0;
            cA0 = __builtin_amdgcn_mfma_f32_16x16x32_bf16(a0.v, bfrag[0], cA0, 0, 0, 0);
            cA1 = __builtin_amdgcn_mfma_f32_16x16x32_bf16(a0.v, bfrag[1], cA1, 0, 0, 0);
            cB0 = __builtin_amdgcn_mfma_f32_16x16x32_bf16(a1.v, bfrag[0], cB0, 0, 0, 0);
            cB1 = __builtin_amdgcn_mfma_f32_16x16x32_bf16(a1.v, bfrag[1], cB1, 0, 0, 0);

            if (t < 3 || quad == 0) {
                int px0 = t * 8 + quad * 2;
                float u0 = fmaxf(fmaxf(cA0[0], cA0[1]), fmaxf(cB0[0], cB0[1]));
                float u1 = fmaxf(fmaxf(cA0[2], cA0[3]), fmaxf(cB0[2], cB0[3]));
                float v0 = fmaxf(fmaxf(cA1[0], cA1[1]), fmaxf(cB1[0], cB1[1]));
                float v1 = fmaxf(fmaxf(cA1[2], cA1[3]), fmaxf(cB1[2], cB1[3]));
                ushort_t* po = out + ((size_t)b * POS + py * 26 + px0) * 32;
                po[lr]           = f2bf(fmaxf(u0 + bv0, 0.0f));
                po[32 + lr]      = f2bf(fmaxf(u1 + bv0, 0.0f));
                po[16 + lr]      = f2bf(fmaxf(v0 + bv1, 0.0f));
                po[32 + 16 + lr] = f2bf(fmaxf(v1 + bv1, 0.0f));
            }
        }
    }
}

// ---------------- k2: conv2 MFMA, 768 blocks x 2 chunks (one residency round) ----------------
__global__ __launch_bounds__(512) void conv2_mfma(const ushort_t* __restrict__ p1,
                                                  const ushort_t* __restrict__ wr,
                                                  const float* __restrict__ bias,
                                                  ushort_t* __restrict__ pool2cl) {
    __shared__ ushort_t lds[260 * ICP];
    int tid = threadIdx.x;
    int lane = tid & 63, wid = tid >> 6;
    int quad = lane >> 4, lr = lane & 15;
    int prow = wid >> 1;
    int nhalf = wid & 1;

#pragma unroll 1
    for (int cc = 0; cc < 2; ++cc) {
        int ch = blockIdx.x * 2 + cc;     // 0..1535
        int b = ch / 3, c = ch % 3;

        const ushort_t* src = p1 + ((size_t)b * POS + 8 * c * 26) * 32;
        for (int t = tid; t < 260 * 8; t += 512) {
            int pos = t >> 3, off = (t & 7) * 4;
            ushort4v v = *reinterpret_cast<const ushort4v*>(src + pos * 32 + off);
            *reinterpret_cast<ushort4v*>(&lds[pos * ICP + off]) = v;
        }
        __syncthreads();

        int ebase[3];
#pragma unroll
        for (int t = 0; t < 3; ++t) {
            int m  = t * 16 + lr;
            int yl = m / 24;
            int xx = m - yl * 24;
            ebase[t] = ((2 * prow + yl) * 26 + xx) * ICP + quad * 8;
        }

        f32x4 acc[3][2];
#pragma unroll
        for (int t = 0; t < 3; ++t)
#pragma unroll
            for (int n = 0; n < 2; ++n) acc[t][n] = (f32x4){0.f, 0.f, 0.f, 0.f};

        const ushort_t* wb = wr + (size_t)(nhalf * 32 + lr) * 288 + quad * 8;

#pragma unroll
        for (int tap = 0; tap < 9; ++tap) {
            int ky = tap / 3, kx = tap % 3;
            int koff = (ky * 26 + kx) * ICP;
            s16x8 a[3];
#pragma unroll
            for (int t = 0; t < 3; ++t) {
                union { ushort4v s[2]; s16x8 v; } u;
                u.s[0] = *reinterpret_cast<const ushort4v*>(&lds[ebase[t] + koff]);
                u.s[1] = *reinterpret_cast<const ushort4v*>(&lds[ebase[t] + koff + 4]);
                a[t] = u.v;
            }
            s16x8 bf[2];
#pragma unroll
            for (int n = 0; n < 2; ++n)
                bf[n] = *reinterpret_cast<const s16x8*>(wb + (size_t)n * 16 * 288 + tap * 32);
#pragma unroll
            for (int t = 0; t < 3; ++t)
#pragma unroll
                for (int n = 0; n < 2; ++n)
                    acc[t][n] = __builtin_amdgcn_mfma_f32_16x16x32_bf16(a[t], bf[n], acc[t][n], 0, 0, 0);
        }
        __syncthreads();

        ushort_t* scr = lds + wid * (32 * SCR);
#pragma unroll
        for (int t = 0; t < 3; ++t)
#pragma unroll
            for (int n = 0; n < 2; ++n) {
                int ocl = n * 16 + lr;
                int i0 = t * 8 + quad * 2;
                float v0 = fmaxf(acc[t][n][0], acc[t][n][1]);
                float v1 = fmaxf(acc[t][n][2], acc[t][n][3]);
                union { ushort_t u2[2]; unsigned w; } pk;
                pk.u2[0] = f2bf(v0); pk.u2[1] = f2bf(v1);
                *reinterpret_cast<unsigned*>(&scr[ocl * SCR + i0]) = pk.w;
            }
        int ocl = lane & 31;
        int pxh = lane >> 5;
        int oc  = nhalf * 32 + ocl;
        const ushort_t* row = scr + ocl * SCR;
        float bv = bias[oc];
        int py = c * 4 + prow;
        ushort_t* po = pool2cl + ((size_t)b * 144 + py * 12) * 64 + oc;
#pragma unroll
        for (int j = 0; j < 6; ++j) {
            int px = pxh * 6 + j;
            float r0 = bf2f(row[px]);
            float r1 = bf2f(row[px + 12]);
            po[px * 64] = f2bf(fmaxf(fmaxf(r0, r1) + bv, 0.0f));
        }
        __syncthreads();   // scr dead before next chunk's restage
    }
}

// ---------------- k3: fc1 bf16 MFMA, 16 K-splits (R12 form) ----------------
__global__ __launch_bounds__(256) void fc1_mfma(const ushort_t* __restrict__ A,
                                                 const ushort_t* __restrict__ W,
                                                 float* __restrict__ Cpart) {
    int tid = threadIdx.x;
    int lane = tid & 63, wid = tid >> 6;
    int lr = lane & 15, quad = lane >> 4;
    int w  = blockIdx.x * 4 + wid;
    int nt = w & 3;
    int ks = (w >> 2) & 15;
    int mt = w >> 6;

    int m0 = mt * 16;
    int n0 = nt * 32;
    int k0 = ks * 576 + quad * 8;
    const ushort_t* a0 = A + (size_t)(m0 + lr) * 9216 + k0;
    const ushort_t* b0 = W + (size_t)(n0 + lr) * 9216 + k0;
    const ushort_t* b1 = b0 + (size_t)16 * 9216;

    f32x4 acc0 = (f32x4){0.f, 0.f, 0.f, 0.f};
    f32x4 acc1 = (f32x4){0.f, 0.f, 0.f, 0.f};

#pragma unroll
    for (int kk = 0; kk < 18; ++kk) {
        s16x8 av  = *reinterpret_cast<const s16x8*>(a0 + kk * 32);
        s16x8 bv0 = *reinterpret_cast<const s16x8*>(b0 + kk * 32);
        s16x8 bv1 = *reinterpret_cast<const s16x8*>(b1 + kk * 32);
        acc0 = __builtin_amdgcn_mfma_f32_16x16x32_bf16(av, bv0, acc0, 0, 0, 0);
        acc1 = __builtin_amdgcn_mfma_f32_16x16x32_bf16(av, bv1, acc1, 0, 0, 0);
    }

    float* cp = Cpart + (size_t)ks * (512 * 128);
    int crow = m0 + quad * 4;
#pragma unroll
    for (int r = 0; r < 4; ++r) {
        cp[(size_t)(crow + r) * 128 + n0 + lr]      = acc0[r];
        cp[(size_t)(crow + r) * 128 + n0 + 16 + lr] = acc1[r];
    }
}

// ---------------- k4: fc1 reduce(16) + bias + relu + fc2 (R12 form) ----------------
__global__ __launch_bounds__(256) void fc1fc2(const float* __restrict__ Cpart,
                                              const float* __restrict__ b1,
                                              const float* __restrict__ w2,
                                              const float* __restrict__ b2,
                                              float* __restrict__ out) {
    __shared__ float h[2][128];
    int half = threadIdx.x >> 7;
    int k = threadIdx.x & 127;
    int b = blockIdx.x * 2 + half;
    float s = 0.f;
#pragma unroll
    for (int ks = 0; ks < 16; ++ks) s += Cpart[(size_t)ks * (512 * 128) + b * 128 + k];
    h[half][k] = fmaxf(s + b1[k], 0.0f);
    __syncthreads();
    if (k < 10) {
        const float* wp = w2 + k * 128;
        float acc = 0.f;
#pragma unroll 8
        for (int j = 0; j < 128; ++j) acc += h[half][j] * wp[j];
        out[b * 10 + k] = acc + b2[k];
    }
}

extern "C" void kernel_launch(void* const* d_in, const int* in_sizes, int n_in,
                              void* d_out, int out_size, void* d_ws, size_t ws_size,
                              hipStream_t stream) {
    const float* x       = (const float*)d_in[0];
    const float* conv1_w = (const float*)d_in[1];
    const float* conv1_b = (const float*)d_in[2];
    const float* conv2_w = (const float*)d_in[3];
    const float* conv2_b = (const float*)d_in[4];
    const float* fc1_w   = (const float*)d_in[5];
    const float* fc1_b   = (const float*)d_in[6];
    const float* fc2_w   = (const float*)d_in[7];
    const float* fc2_b   = (const float*)d_in[8];
    float* out = (float*)d_out;

    char* ws = (char*)d_ws;
    ushort_t* pool1 = (ushort_t*)ws;
    ws += (size_t)B * POS * 32 * sizeof(ushort_t);
    ushort_t* wr = (ushort_t*)ws;
    ws += N_WR * sizeof(ushort_t) + 128;
    ushort_t* wfb = (ushort_t*)ws;
    ws += (size_t)128 * 9216 * sizeof(ushort_t) + 128;
    ushort_t* pool2cl = (ushort_t*)ws;
    ws += (size_t)B * P2SZ * sizeof(ushort_t) + 128;
    float* Cpart = (float*)ws;
    ws += (size_t)16 * 512 * 128 * sizeof(float) + 128;

    conv1_prep<<<PRE_BLOCKS + CONV1_BLOCKS, 256, 0, stream>>>(
        x, conv1_w, conv1_b, conv2_w, fc1_w, pool1, wr, wfb);
    conv2_mfma<<<768, 512, 0, stream>>>(pool1, wr, conv2_b, pool2cl);
    fc1_mfma<<<512, 256, 0, stream>>>(pool2cl, wfb, Cpart);
    fc1fc2<<<256, 256, 0, stream>>>(Cpart, fc1_b, fc2_w, fc2_b, out);
}

// Round 16
// 127.679 us; speedup vs baseline: 1.0531x; 1.0531x over previous
//
#include <hip/hip_runtime.h>

// LNSNet forward, R15 = R13 verbatim (best: 127.6us, absmax 0.0239).
// R14's 768x2-chunk conv2 regressed (+7us): block scheduler is greedy, not
// round-based -- many small blocks beat fewer sequential-work blocks.
// Structure: k1 [conv1-MFMA | conv2-w prep | fc1-W transpose], k2 conv2 MFMA
// (1536 small blocks), k3 fc1 MFMA split-K(16), k4 reduce+bias+relu+fc2.
// Standing lessons: no device-scope fences (R6/R9); no launch_bounds forcing
// near register budget (R10); don't serialize per-block work (R14).

#define B 512
#define POS 676
#define ICP 36
#define P2SZ (64*12*12)
#define SCR 26
#define IMS 58                  // LDS image row stride (ushorts), odd dwords
#define IMCOPY (54 * IMS)       // 3132 ushorts per copy

typedef unsigned short ushort_t;
typedef ushort_t ushort4v __attribute__((ext_vector_type(4)));
typedef short s16x8 __attribute__((ext_vector_type(8)));
typedef float f32x4 __attribute__((ext_vector_type(4)));

__device__ __forceinline__ ushort_t f2bf(float f) {
    union { float f; unsigned u; } a; a.f = f;
    unsigned r = a.u + 0x7FFFu + ((a.u >> 16) & 1u);
    return (ushort_t)(r >> 16);
}
__device__ __forceinline__ float bf2f(ushort_t u) {
    union { unsigned u; float f; } a; a.u = ((unsigned)u) << 16;
    return a.f;
}

#define N_WR (64 * 9 * 32)
#define CONV1_BLOCKS 1024       // 2 per image
#define WR_BLOCKS 72
#define TR_BLOCKS 128

// ---------------- k1: conv1 MFMA + wr prep + fc1-W transpose ----------------
__global__ __launch_bounds__(256) void conv1_prep(const float* __restrict__ x,
                                                  const float* __restrict__ w,
                                                  const float* __restrict__ bias,
                                                  const float* __restrict__ c2w,
                                                  const float* __restrict__ f1w,
                                                  ushort_t* __restrict__ out,
                                                  ushort_t* __restrict__ wr,
                                                  ushort_t* __restrict__ wfb) {
    __shared__ char smem[64 * 145 * 4];     // 37,120 B, aliased per branch
    int blk = blockIdx.x;
    int tid = threadIdx.x;

    if (blk >= CONV1_BLOCKS + WR_BLOCKS) {
        // ---- fc1 W transpose via LDS tile ----
        float* tr = reinterpret_cast<float*>(smem);   // 64 x 145
        int n = blk - CONV1_BLOCKS - WR_BLOCKS;
        const float* src = f1w + (size_t)n * 9216;
#pragma unroll
        for (int i = 0; i < 36; ++i) {
            int idx = i * 256 + tid;
            int oc = idx / 144, pos = idx - oc * 144;
            tr[oc * 145 + pos] = src[idx];
        }
        __syncthreads();
        ushort_t* dst = wfb + (size_t)n * 9216;
#pragma unroll
        for (int i = 0; i < 36; ++i) {
            int idx = i * 256 + tid;
            int pos = idx >> 6, oc = idx & 63;
            dst[idx] = f2bf(tr[oc * 145 + pos]);
        }
        return;
    }
    if (blk >= CONV1_BLOCKS) {
        int t = (blk - CONV1_BLOCKS) * 256 + tid;
        int ic  = t & 31;
        int tap = (t >> 5) % 9;
        int oc  = t / 288;
        wr[t] = f2bf(c2w[oc * 288 + ic * 9 + tap]);
        return;
    }

    // ================= conv1 via MFMA =================
    ushort_t* lds = reinterpret_cast<ushort_t*>(smem);   // 2 copies = 12,528 ushorts
    int b    = blk >> 1;
    int half = blk & 1;

    const float* xim = x + (size_t)b * 2916;
    for (int i = tid; i < 2916; i += 256) {
        int r = i / 54, c = i - r * 54;
        ushort_t v = f2bf(xim[i]);
        lds[r * IMS + c] = v;
        if (c > 0) lds[IMCOPY + r * IMS + c - 1] = v;
    }

    int lane = tid & 63, wid = tid >> 6;
    int quad = lane >> 4, lr = lane & 15;

    // B-frags: w[oc][ky=quad][kx=0..2], zeros elsewhere (incl quad==3)
    s16x8 bfrag[2];
#pragma unroll
    for (int n = 0; n < 2; ++n) {
        union { ushort_t u[8]; s16x8 v; } bu;
#pragma unroll
        for (int j = 0; j < 8; ++j) bu.u[j] = 0;
        if (quad < 3) {
            const float* wp = w + (n * 16 + lr) * 9 + quad * 3;
            bu.u[0] = f2bf(wp[0]);
            bu.u[1] = f2bf(wp[1]);
            bu.u[2] = f2bf(wp[2]);
        }
        bfrag[n] = bu.v;
    }
    float bv0 = bias[lr], bv1 = bias[16 + lr];

    __syncthreads();

    // even lanes read copy0 at col x0+lr; odd lanes copy1 at col x0+lr-1
    int cbase = (lr & 1) ? (IMCOPY + lr - 1) : lr;

    for (int py_l = wid; py_l < 13; py_l += 4) {
        int py = half * 13 + py_l;
        int y0 = 2 * py;
#pragma unroll
        for (int t = 0; t < 4; ++t) {
            int x0 = t * 16;
            int off0 = cbase + x0 + (y0 + quad) * IMS;
            int off1 = off0 + IMS;
            union { unsigned d[4]; s16x8 v; } a0, a1;
            a0.d[0] = *reinterpret_cast<const unsigned*>(&lds[off0]);
            a0.d[1] = *reinterpret_cast<const unsigned*>(&lds[off0 + 2]);
            a0.d[2] = a0.d[0]; a0.d[3] = a0.d[1];     // k slots 4..7: zero-weighted
            a1.d[0] = *reinterpret_cast<const unsigned*>(&lds[off1]);
            a1.d[1] = *reinterpret_cast<const unsigned*>(&lds[off1 + 2]);
            a1.d[2] = a1.d[0]; a1.d[3] = a1.d[1];

            f32x4 cA0 = (f32x4){0.f,0.f,0.f,0.f}, cA1 = cA0, cB0 = cA0, cB1 = cA0;
            cA0 = __builtin_amdgcn_mfma_f32_16x16x32_bf16(a0.v, bfrag[0], cA0, 0, 0, 0);
            cA1 = __builtin_amdgcn_mfma_f32_16x16x32_bf16(a0.v, bfrag[1], cA1, 0, 0, 0);
            cB0 = __builtin_amdgcn_mfma_f32_16x16x32_bf16(a1.v, bfrag[0], cB0, 0, 0, 0);
            cB1 = __builtin_amdgcn_mfma_f32_16x16x32_bf16(a1.v, bfrag[1], cB1, 0, 0, 0);

            if (t < 3 || quad == 0) {
                int px0 = t * 8 + quad * 2;
                float u0 = fmaxf(fmaxf(cA0[0], cA0[1]), fmaxf(cB0[0], cB0[1]));
                float u1 = fmaxf(fmaxf(cA0[2], cA0[3]), fmaxf(cB0[2], cB0[3]));
                float v0 = fmaxf(fmaxf(cA1[0], cA1[1]), fmaxf(cB1[0], cB1[1]));
                float v1 = fmaxf(fmaxf(cA1[2], cA1[3]), fmaxf(cB1[2], cB1[3]));
                ushort_t* po = out + ((size_t)b * POS + py * 26 + px0) * 32;
                po[lr]           = f2bf(fmaxf(u0 + bv0, 0.0f));
                po[32 + lr]      = f2bf(fmaxf(u1 + bv0, 0.0f));
                po[16 + lr]      = f2bf(fmaxf(v0 + bv1, 0.0f));
                po[32 + 16 + lr] = f2bf(fmaxf(v1 + bv1, 0.0f));
            }
        }
    }
}

// ---------------- k2: conv2 MFMA, 1536 small blocks (512 thr, 8 waves) ----------------
__global__ __launch_bounds__(512) void conv2_mfma(const ushort_t* __restrict__ p1,
                                                  const ushort_t* __restrict__ wr,
                                                  const float* __restrict__ bias,
                                                  ushort_t* __restrict__ pool2cl) {
    __shared__ ushort_t lds[260 * ICP];
    int blk = blockIdx.x;
    int b = blk / 3, c = blk % 3;
    int tid = threadIdx.x;

    const ushort_t* src = p1 + ((size_t)b * POS + 8 * c * 26) * 32;
    for (int t = tid; t < 260 * 8; t += 512) {
        int pos = t >> 3, off = (t & 7) * 4;
        ushort4v v = *reinterpret_cast<const ushort4v*>(src + pos * 32 + off);
        *reinterpret_cast<ushort4v*>(&lds[pos * ICP + off]) = v;
    }
    __syncthreads();

    int lane = tid & 63, wid = tid >> 6;
    int quad = lane >> 4, lr = lane & 15;
    int prow = wid >> 1;
    int nhalf = wid & 1;

    int ebase[3];
#pragma unroll
    for (int t = 0; t < 3; ++t) {
        int m  = t * 16 + lr;
        int yl = m / 24;
        int xx = m - yl * 24;
        ebase[t] = ((2 * prow + yl) * 26 + xx) * ICP + quad * 8;
    }

    f32x4 acc[3][2];
#pragma unroll
    for (int t = 0; t < 3; ++t)
#pragma unroll
        for (int n = 0; n < 2; ++n) acc[t][n] = (f32x4){0.f, 0.f, 0.f, 0.f};

    const ushort_t* wb = wr + (size_t)(nhalf * 32 + lr) * 288 + quad * 8;

#pragma unroll
    for (int tap = 0; tap < 9; ++tap) {
        int ky = tap / 3, kx = tap % 3;
        int koff = (ky * 26 + kx) * ICP;
        s16x8 a[3];
#pragma unroll
        for (int t = 0; t < 3; ++t) {
            union { ushort4v s[2]; s16x8 v; } u;
            u.s[0] = *reinterpret_cast<const ushort4v*>(&lds[ebase[t] + koff]);
            u.s[1] = *reinterpret_cast<const ushort4v*>(&lds[ebase[t] + koff + 4]);
            a[t] = u.v;
        }
        s16x8 bf[2];
#pragma unroll
        for (int n = 0; n < 2; ++n)
            bf[n] = *reinterpret_cast<const s16x8*>(wb + (size_t)n * 16 * 288 + tap * 32);
#pragma unroll
        for (int t = 0; t < 3; ++t)
#pragma unroll
            for (int n = 0; n < 2; ++n)
                acc[t][n] = __builtin_amdgcn_mfma_f32_16x16x32_bf16(a[t], bf[n], acc[t][n], 0, 0, 0);
    }
    __syncthreads();

    ushort_t* scr = lds + wid * (32 * SCR);
#pragma unroll
    for (int t = 0; t < 3; ++t)
#pragma unroll
        for (int n = 0; n < 2; ++n) {
            int ocl = n * 16 + lr;
            int i0 = t * 8 + quad * 2;
            float v0 = fmaxf(acc[t][n][0], acc[t][n][1]);
            float v1 = fmaxf(acc[t][n][2], acc[t][n][3]);
            union { ushort_t u2[2]; unsigned w; } pk;
            pk.u2[0] = f2bf(v0); pk.u2[1] = f2bf(v1);
            *reinterpret_cast<unsigned*>(&scr[ocl * SCR + i0]) = pk.w;
        }
    int ocl = lane & 31;
    int pxh = lane >> 5;
    int oc  = nhalf * 32 + ocl;
    const ushort_t* row = scr + ocl * SCR;
    float bv = bias[oc];
    int py = c * 4 + prow;
    ushort_t* po = pool2cl + ((size_t)b * 144 + py * 12) * 64 + oc;
#pragma unroll
    for (int j = 0; j < 6; ++j) {
        int px = pxh * 6 + j;
        float r0 = bf2f(row[px]);
        float r1 = bf2f(row[px + 12]);
        po[px * 64] = f2bf(fmaxf(fmaxf(r0, r1) + bv, 0.0f));
    }
}

// ---------------- k3: fc1 bf16 MFMA, 16 K-splits ----------------
__global__ __launch_bounds__(256) void fc1_mfma(const ushort_t* __restrict__ A,
                                                 const ushort_t* __restrict__ W,
                                                 float* __restrict__ Cpart) {
    int tid = threadIdx.x;
    int lane = tid & 63, wid = tid >> 6;
    int lr = lane & 15, quad = lane >> 4;
    int w  = blockIdx.x * 4 + wid;
    int nt = w & 3;
    int ks = (w >> 2) & 15;
    int mt = w >> 6;

    int m0 = mt * 16;
    int n0 = nt * 32;
    int k0 = ks * 576 + quad * 8;
    const ushort_t* a0 = A + (size_t)(m0 + lr) * 9216 + k0;
    const ushort_t* b0 = W + (size_t)(n0 + lr) * 9216 + k0;
    const ushort_t* b1 = b0 + (size_t)16 * 9216;

    f32x4 acc0 = (f32x4){0.f, 0.f, 0.f, 0.f};
    f32x4 acc1 = (f32x4){0.f, 0.f, 0.f, 0.f};

#pragma unroll
    for (int kk = 0; kk < 18; ++kk) {
        s16x8 av  = *reinterpret_cast<const s16x8*>(a0 + kk * 32);
        s16x8 bv0 = *reinterpret_cast<const s16x8*>(b0 + kk * 32);
        s16x8 bv1 = *reinterpret_cast<const s16x8*>(b1 + kk * 32);
        acc0 = __builtin_amdgcn_mfma_f32_16x16x32_bf16(av, bv0, acc0, 0, 0, 0);
        acc1 = __builtin_amdgcn_mfma_f32_16x16x32_bf16(av, bv1, acc1, 0, 0, 0);
    }

    float* cp = Cpart + (size_t)ks * (512 * 128);
    int crow = m0 + quad * 4;
#pragma unroll
    for (int r = 0; r < 4; ++r) {
        cp[(size_t)(crow + r) * 128 + n0 + lr]      = acc0[r];
        cp[(size_t)(crow + r) * 128 + n0 + 16 + lr] = acc1[r];
    }
}

// ---------------- k4: fc1 reduce(16) + bias + relu + fc2 ----------------
__global__ __launch_bounds__(256) void fc1fc2(const float* __restrict__ Cpart,
                                              const float* __restrict__ b1,
                                              const float* __restrict__ w2,
                                              const float* __restrict__ b2,
                                              float* __restrict__ out) {
    __shared__ float h[2][128];
    int half = threadIdx.x >> 7;
    int k = threadIdx.x & 127;
    int b = blockIdx.x * 2 + half;
    float s = 0.f;
#pragma unroll
    for (int ks = 0; ks < 16; ++ks) s += Cpart[(size_t)ks * (512 * 128) + b * 128 + k];
    h[half][k] = fmaxf(s + b1[k], 0.0f);
    __syncthreads();
    if (k < 10) {
        const float* wp = w2 + k * 128;
        float acc = 0.f;
#pragma unroll 8
        for (int j = 0; j < 128; ++j) acc += h[half][j] * wp[j];
        out[b * 10 + k] = acc + b2[k];
    }
}

extern "C" void kernel_launch(void* const* d_in, const int* in_sizes, int n_in,
                              void* d_out, int out_size, void* d_ws, size_t ws_size,
                              hipStream_t stream) {
    const float* x       = (const float*)d_in[0];
    const float* conv1_w = (const float*)d_in[1];
    const float* conv1_b = (const float*)d_in[2];
    const float* conv2_w = (const float*)d_in[3];
    const float* conv2_b = (const float*)d_in[4];
    const float* fc1_w   = (const float*)d_in[5];
    const float* fc1_b   = (const float*)d_in[6];
    const float* fc2_w   = (const float*)d_in[7];
    const float* fc2_b   = (const float*)d_in[8];
    float* out = (float*)d_out;

    char* ws = (char*)d_ws;
    ushort_t* pool1 = (ushort_t*)ws;
    ws += (size_t)B * POS * 32 * sizeof(ushort_t);
    ushort_t* wr = (ushort_t*)ws;
    ws += N_WR * sizeof(ushort_t) + 128;
    ushort_t* wfb = (ushort_t*)ws;
    ws += (size_t)128 * 9216 * sizeof(ushort_t) + 128;
    ushort_t* pool2cl = (ushort_t*)ws;
    ws += (size_t)B * P2SZ * sizeof(ushort_t) + 128;
    float* Cpart = (float*)ws;
    ws += (size_t)16 * 512 * 128 * sizeof(float) + 128;

    conv1_prep<<<CONV1_BLOCKS + WR_BLOCKS + TR_BLOCKS, 256, 0, stream>>>(
        x, conv1_w, conv1_b, conv2_w, fc1_w, pool1, wr, wfb);
    conv2_mfma<<<B * 3, 512, 0, stream>>>(pool1, wr, conv2_b, pool2cl);
    fc1_mfma<<<512, 256, 0, stream>>>(pool2cl, wfb, Cpart);
    fc1fc2<<<256, 256, 0, stream>>>(Cpart, fc1_b, fc2_w, fc2_b, out);
}